// Round 4
// baseline (620.685 us; speedup 1.0000x reference)
//
#include <hip/hip_runtime.h>
#include <hip/hip_bf16.h>

#define BB 256
#define TT 512
#define EE 300
#define G4 200     // 4*H1
#define JP 256     // padded gate dim for Wt
#define BKP 60     // proj LDS stage depth (300 = 5*60)

// permuted gate col: G1 column jp corresponds to W row (jp&3)*50 + (jp>>2),
// so thread tid==jp in lstm has gates (i,f,g,o) of unit u=tid>>2 in its quad.

__device__ __forceinline__ float sigm(float x) {
    return __builtin_amdgcn_rcpf(1.f + __builtin_amdgcn_exp2f(-1.442695040888963f * x));
}
__device__ __forceinline__ float tanh_(float x) {
    float t = __builtin_amdgcn_exp2f(2.885390081777927f * x);   // e^(2x)
    return 1.f - 2.f * __builtin_amdgcn_rcpf(t + 1.f);
}

// quad broadcast via DPP: lane gets value from (quad base + K) — 1 VALU op
template <int C>
__device__ __forceinline__ float qb(float v) {
    return __int_as_float(__builtin_amdgcn_mov_dpp(__float_as_int(v), C, 0xF, 0xF, true));
}

// raw barrier: LDS-visibility only; leaves global loads in flight (no vmcnt drain)
__device__ __forceinline__ void lds_barrier() {
    asm volatile("s_waitcnt lgkmcnt(0)" ::: "memory");
    __builtin_amdgcn_s_barrier();
}

// ---------------------------------------------------------------------------
// K1: permuted transpose + zero-pad W_ih1 [200,300] -> Wt [300][256]
__global__ void wtrans_kernel(const float* __restrict__ W, float* __restrict__ Wt) {
    int e = blockIdx.x;        // 0..299
    int j = threadIdx.x;       // 0..255
    float v = 0.f;
    if (j < G4) {
        int row = (j & 3) * 50 + (j >> 2);
        v = W[row * EE + e];
    }
    Wt[e * JP + j] = v;
}

// ---------------------------------------------------------------------------
// K2: G1[bb][t][jp] = b1[row(jp)] + emb[x[b][t]] . W_ih1[row(jp)]
__device__ __forceinline__ float f4get(const float4& v, int u) {
    return u == 0 ? v.x : u == 1 ? v.y : u == 2 ? v.z : v.w;
}

__global__ __launch_bounds__(256) void proj_kernel(
    const int* __restrict__ x, const int* __restrict__ lengths,
    const float* __restrict__ emb, const float* __restrict__ b1,
    const float* __restrict__ Wt, float* __restrict__ G1, int b0)
{
    const int b  = b0 + blockIdx.y;
    const int t0 = blockIdx.x * 64;
    const int len = lengths[b];
    if (t0 >= len) return;                       // uniform: whole tile padding

    const int tid = threadIdx.x;
    const int rg  = tid >> 5;                    // 0..7 : rows rg*8 .. rg*8+7
    const int jg  = tid & 31;                    // col groups; valid if jg<25
    const bool active = (jg < 25);

    __shared__ float4 Ws4[BKP * 50];             // 48 KB: [k][c4]

    const float* er[8];
    #pragma unroll
    for (int q = 0; q < 8; ++q)
        er[q] = emb + (size_t)x[b * TT + t0 + rg * 8 + q] * EE;

    float acc[8][8];
    {
        float bv[8];
        #pragma unroll
        for (int k = 0; k < 8; ++k) {
            int c = (k < 4) ? (4 * jg + k) : (96 + 4 * jg + k);
            bv[k] = active ? b1[(c & 3) * 50 + (c >> 2)] : 0.f;
        }
        #pragma unroll
        for (int q = 0; q < 8; ++q)
            #pragma unroll
            for (int k = 0; k < 8; ++k) acc[q][k] = bv[k];
    }

    const float4* Wt4 = (const float4*)Wt;       // [300][64] float4s

    // prefetch first a-slice (e=0..3)
    float4 avn[8];
    #pragma unroll
    for (int q = 0; q < 8; ++q) avn[q] = *(const float4*)(er[q]);

    for (int s = 0; s < 5; ++s) {
        const int e0 = s * BKP;
        // ---- stage Wt[e0..e0+59][0..199] into LDS (coalesced)
        for (int i = tid; i < BKP * 50; i += 256) {
            int r = i / 50;
            int c = i - r * 50;
            Ws4[i] = Wt4[(size_t)(e0 + r) * (JP / 4) + c];
        }
        lds_barrier();                            // av prefetch stays in flight

        for (int kk = 0; kk < BKP / 4; ++kk) {
            float4 av[8];
            #pragma unroll
            for (int q = 0; q < 8; ++q) av[q] = avn[q];
            const int en = e0 + kk * 4 + 4;       // next slice (may cross stage)
            if (en < EE) {
                #pragma unroll
                for (int q = 0; q < 8; ++q)
                    avn[q] = *(const float4*)(er[q] + en);
            }
            if (active) {
                #pragma unroll
                for (int u = 0; u < 4; ++u) {
                    float4 w0 = Ws4[(kk * 4 + u) * 50 + jg];
                    float4 w1 = Ws4[(kk * 4 + u) * 50 + 25 + jg];
                    #pragma unroll
                    for (int q = 0; q < 8; ++q) {
                        float a = f4get(av[q], u);
                        acc[q][0] = fmaf(a, w0.x, acc[q][0]);
                        acc[q][1] = fmaf(a, w0.y, acc[q][1]);
                        acc[q][2] = fmaf(a, w0.z, acc[q][2]);
                        acc[q][3] = fmaf(a, w0.w, acc[q][3]);
                        acc[q][4] = fmaf(a, w1.x, acc[q][4]);
                        acc[q][5] = fmaf(a, w1.y, acc[q][5]);
                        acc[q][6] = fmaf(a, w1.z, acc[q][6]);
                        acc[q][7] = fmaf(a, w1.w, acc[q][7]);
                    }
                }
            }
        }
        __builtin_amdgcn_s_barrier();             // Ws4 reads consumed (data deps)
    }

    if (active) {
        float* gbase = G1 + ((size_t)blockIdx.y * TT + t0) * G4;
        #pragma unroll
        for (int q = 0; q < 8; ++q) {
            float* gp = gbase + (size_t)(rg * 8 + q) * G4;
            *(float4*)(gp + 4 * jg)       = make_float4(acc[q][0], acc[q][1], acc[q][2], acc[q][3]);
            *(float4*)(gp + 100 + 4 * jg) = make_float4(acc[q][4], acc[q][5], acc[q][6], acc[q][7]);
        }
    }
}

// ---------------------------------------------------------------------------
// K3: recurrence. One block (320 thr) per batch element, 1 raw barrier/step.
// tid 0..199   : LSTM1 row (tid&3)*50+(tid>>2)  (waves 0..3, quad = unit)
// tid 256..295 : LSTM2 row (q&3)*10+(q>>2), q=tid-256 (wave 4), lags 1 step
__global__ __launch_bounds__(320, 1) void lstm_kernel(
    const int* __restrict__ lengths,
    const float* __restrict__ W_hh1, const float* __restrict__ W_ih2,
    const float* __restrict__ W_hh2, const float* __restrict__ b2,
    const float* __restrict__ fc1w, const float* __restrict__ fc1b,
    const float* __restrict__ fc2w, const float* __restrict__ fc2b,
    const float* __restrict__ G1, float* __restrict__ out, int b0)
{
    const int bb  = blockIdx.x;
    const int b   = b0 + bb;
    const int tid = threadIdx.x;
    const int len = lengths[b];

    __shared__ __align__(16) float h1s[2][52];
    __shared__ __align__(16) float h2s[2][12];
    __shared__ __align__(16) float hfin[12];
    __shared__ float zbuf[10];

    if (tid < 52) { h1s[0][tid] = 0.f; h1s[1][tid] = 0.f; }
    if (tid < 12) { h2s[0][tid] = 0.f; h2s[1][tid] = 0.f; }

    const bool is1 = (tid < 200);
    const bool is2 = (tid >= 256 && tid < 296);

    float wreg[52];                 // LSTM1: W_hh1 row | LSTM2: W_ih2 row
    float wregb[12];                // LSTM2: W_hh2 row
    #pragma unroll
    for (int k = 0; k < 52; ++k) wreg[k] = 0.f;
    #pragma unroll
    for (int k = 0; k < 12; ++k) wregb[k] = 0.f;
    float b2r = 0.f;

    if (is1) {
        int u = tid >> 2, g = tid & 3;
        const float* wp = W_hh1 + (g * 50 + u) * 50;
        #pragma unroll
        for (int k = 0; k < 50; ++k) wreg[k] = wp[k];
    } else if (is2) {
        int q = tid - 256, u = q >> 2, g = q & 3;
        int row = g * 10 + u;
        const float* wp = W_ih2 + row * 50;
        #pragma unroll
        for (int k = 0; k < 50; ++k) wreg[k] = wp[k];
        const float* wp2 = W_hh2 + row * 10;
        #pragma unroll
        for (int k = 0; k < 10; ++k) wregb[k] = wp2[k];
        b2r = b2[row];
    }
    // pin weights into VGPRs: forbid rematerialization-from-global per step
    #pragma unroll
    for (int k = 0; k < 52; ++k) asm volatile("" : "+v"(wreg[k]));
    #pragma unroll
    for (int k = 0; k < 12; ++k) asm volatile("" : "+v"(wregb[k]));
    asm volatile("" : "+v"(b2r));

    float h1v[52], h2v[12];
    #pragma unroll
    for (int k = 0; k < 52; ++k) h1v[k] = 0.f;
    #pragma unroll
    for (int k = 0; k < 12; ++k) h2v[k] = 0.f;

    float c1 = 0.f, c2 = 0.f;
    const float* g1p = G1 + (size_t)bb * TT * G4;
    float g0 = 0.f, g1r = 0.f, g2r = 0.f;        // 3-deep rotation (2-step slack)
    if (is1) {
        g0 = g1p[tid];
        int t1 = (1 < len) ? 1 : len - 1;
        int t2 = (2 < len) ? 2 : len - 1;
        g1r = g1p[(size_t)t1 * G4 + tid];
        g2r = g1p[(size_t)t2 * G4 + tid];
    }

    __syncthreads();                               // LDS zero-init visible

    for (int i = 0; i < len; ++i) {
        if (is1) {
            float g = g0;
            g0 = g1r; g1r = g2r;
            int tn = (i + 3 < len) ? i + 3 : len - 1;
            g2r = g1p[(size_t)tn * G4 + tid];       // prefetch 3 ahead
            float s0 = 0.f, s1 = 0.f, s2 = 0.f, s3 = 0.f;
            #pragma unroll
            for (int m = 0; m < 13; ++m) {
                s0 = fmaf(wreg[4*m+0], h1v[4*m+0], s0);
                s1 = fmaf(wreg[4*m+1], h1v[4*m+1], s1);
                s2 = fmaf(wreg[4*m+2], h1v[4*m+2], s2);
                s3 = fmaf(wreg[4*m+3], h1v[4*m+3], s3);
            }
            float gv = g + (s0 + s1) + (s2 + s3);
            float gi = qb<0x00>(gv);
            float gf = qb<0x55>(gv);
            float gg = qb<0xAA>(gv);
            float go = qb<0xFF>(gv);
            float cn = sigm(gf) * c1 + sigm(gi) * tanh_(gg);
            c1 = cn;
            float hn = sigm(go) * tanh_(cn);
            if ((tid & 3) == 0) h1s[i & 1][tid >> 2] = hn;
        } else if (is2 && i >= 1) {
            float s0 = 0.f, s1 = 0.f, s2 = 0.f, s3 = 0.f;
            #pragma unroll
            for (int m = 0; m < 13; ++m) {
                s0 = fmaf(wreg[4*m+0], h1v[4*m+0], s0);
                s1 = fmaf(wreg[4*m+1], h1v[4*m+1], s1);
                s2 = fmaf(wreg[4*m+2], h1v[4*m+2], s2);
                s3 = fmaf(wreg[4*m+3], h1v[4*m+3], s3);
            }
            #pragma unroll
            for (int m = 0; m < 3; ++m) {
                s0 = fmaf(wregb[4*m+0], h2v[4*m+0], s0);
                s1 = fmaf(wregb[4*m+1], h2v[4*m+1], s1);
                s2 = fmaf(wregb[4*m+2], h2v[4*m+2], s2);
                s3 = fmaf(wregb[4*m+3], h2v[4*m+3], s3);
            }
            float gv = b2r + (s0 + s1) + (s2 + s3);
            float gi = qb<0x00>(gv);
            float gf = qb<0x55>(gv);
            float gg = qb<0xAA>(gv);
            float go = qb<0xFF>(gv);
            float cn = sigm(gf) * c2 + sigm(gi) * tanh_(gg);
            c2 = cn;
            float hn = sigm(go) * tanh_(cn);
            if ((tid & 3) == 0) h2s[i & 1][(tid - 256) >> 2] = hn;
        }
        lds_barrier();                              // G1 prefetch stays in flight
        // reload h(i) into regs from the buffer written this iteration
        {
            const float* hb = h1s[i & 1];
            #pragma unroll
            for (int m = 0; m < 13; ++m) {
                float4 v = *(const float4*)(hb + 4 * m);
                h1v[4*m+0] = v.x; h1v[4*m+1] = v.y;
                h1v[4*m+2] = v.z; h1v[4*m+3] = v.w;
            }
            if (tid >= 256) {                       // wave-uniform guard
                const float* hb2 = h2s[i & 1];
                #pragma unroll
                for (int m = 0; m < 3; ++m) {
                    float4 v = *(const float4*)(hb2 + 4 * m);
                    h2v[4*m+0] = v.x; h2v[4*m+1] = v.y;
                    h2v[4*m+2] = v.z; h2v[4*m+3] = v.w;
                }
            }
        }
    }

    // ---- tail: h2(len-1) from h1(len-1), h2(len-2)
    if (is2) {
        float s0 = 0.f, s1 = 0.f, s2 = 0.f, s3 = 0.f;
        #pragma unroll
        for (int m = 0; m < 13; ++m) {
            s0 = fmaf(wreg[4*m+0], h1v[4*m+0], s0);
            s1 = fmaf(wreg[4*m+1], h1v[4*m+1], s1);
            s2 = fmaf(wreg[4*m+2], h1v[4*m+2], s2);
            s3 = fmaf(wreg[4*m+3], h1v[4*m+3], s3);
        }
        #pragma unroll
        for (int m = 0; m < 3; ++m) {
            s0 = fmaf(wregb[4*m+0], h2v[4*m+0], s0);
            s1 = fmaf(wregb[4*m+1], h2v[4*m+1], s1);
            s2 = fmaf(wregb[4*m+2], h2v[4*m+2], s2);
            s3 = fmaf(wregb[4*m+3], h2v[4*m+3], s3);
        }
        float gv = b2r + (s0 + s1) + (s2 + s3);
        float gi = qb<0x00>(gv);
        float gf = qb<0x55>(gv);
        float gg = qb<0xAA>(gv);
        float go = qb<0xFF>(gv);
        float cn = sigm(gf) * c2 + sigm(gi) * tanh_(gg);
        float hn = sigm(go) * tanh_(cn);
        if ((tid & 3) == 0) hfin[(tid - 256) >> 2] = hn;
    }
    __syncthreads();

    // ---- MLP head
    if (tid < 10) {
        float s = fc1b[tid];
        #pragma unroll
        for (int e = 0; e < 10; ++e) s = fmaf(fc1w[tid * 10 + e], hfin[e], s);
        zbuf[tid] = s > 0.f ? s : 0.f;
    }
    __syncthreads();
    if (tid == 0) {
        float s = fc2b[0];
        #pragma unroll
        for (int e = 0; e < 10; ++e) s = fmaf(fc2w[e], zbuf[e], s);
        out[b] = s;
    }
}

// ---------------------------------------------------------------------------
extern "C" void kernel_launch(void* const* d_in, const int* in_sizes, int n_in,
                              void* d_out, int out_size, void* d_ws, size_t ws_size,
                              hipStream_t stream)
{
    const int*   x     = (const int*)  d_in[0];
    const int*   len   = (const int*)  d_in[1];
    const float* emb   = (const float*)d_in[2];
    const float* W_ih1 = (const float*)d_in[3];
    const float* W_hh1 = (const float*)d_in[4];
    const float* b1    = (const float*)d_in[5];
    const float* W_ih2 = (const float*)d_in[6];
    const float* W_hh2 = (const float*)d_in[7];
    const float* b2    = (const float*)d_in[8];
    const float* fc1w  = (const float*)d_in[9];
    const float* fc1b  = (const float*)d_in[10];
    const float* fc2w  = (const float*)d_in[11];
    const float* fc2b  = (const float*)d_in[12];
    float* out = (float*)d_out;

    const size_t wt_bytes = (size_t)EE * JP * sizeof(float);     // 307200
    const size_t per_b    = (size_t)TT * G4 * sizeof(float);     // 409600
    float* Wt = (float*)d_ws;
    float* G1 = (float*)((char*)d_ws + wt_bytes);

    size_t avail = ws_size > wt_bytes ? ws_size - wt_bytes : 0;
    int chunk = (int)(avail / per_b);
    if (chunk < 1) chunk = 1;
    if (chunk > BB) chunk = BB;

    wtrans_kernel<<<dim3(EE), dim3(256), 0, stream>>>(W_ih1, Wt);

    for (int b0 = 0; b0 < BB; b0 += chunk) {
        int nb = (BB - b0) < chunk ? (BB - b0) : chunk;
        proj_kernel<<<dim3(TT / 64, nb), dim3(256), 0, stream>>>(
            x, len, emb, b1, Wt, G1, b0);
        lstm_kernel<<<dim3(nb), dim3(320), 0, stream>>>(
            len, W_hh1, W_ih2, W_hh2, b2, fc1w, fc1b, fc2w, fc2b, G1, out, b0);
    }
}

// Round 5
// 510.313 us; speedup vs baseline: 1.2163x; 1.2163x over previous
//
#include <hip/hip_runtime.h>
#include <hip/hip_bf16.h>

#define BB 256
#define TT 512
#define EE 300
#define G4 200     // 4*H1
#define JP 256     // padded gate dim for Wt
#define BKP 60     // proj LDS stage depth (300 = 5*60)

// permuted gate col: G1 column jp corresponds to W row (jp&3)*50 + (jp>>2),
// so thread tid==jp in lstm has gates (i,f,g,o) of unit u=tid>>2 in its quad.

__device__ __forceinline__ float sigm(float x) {
    return __builtin_amdgcn_rcpf(1.f + __builtin_amdgcn_exp2f(-1.442695040888963f * x));
}
__device__ __forceinline__ float tanh_(float x) {
    float t = __builtin_amdgcn_exp2f(2.885390081777927f * x);   // e^(2x)
    return 1.f - 2.f * __builtin_amdgcn_rcpf(t + 1.f);
}

// quad broadcast via DPP: lane gets value from (quad base + K) — 1 VALU op
template <int C>
__device__ __forceinline__ float qb(float v) {
    return __int_as_float(__builtin_amdgcn_mov_dpp(__float_as_int(v), C, 0xF, 0xF, true));
}

// producer barrier: make LDS writes visible, leave global loads in flight.
// asm waitcnt (no reorder past: memory clobber) + barrier + sched fence (rule #18)
__device__ __forceinline__ void lds_producer_barrier() {
    asm volatile("s_waitcnt lgkmcnt(0)" ::: "memory");
    __builtin_amdgcn_s_barrier();
    __builtin_amdgcn_sched_barrier(0);
}
// consumer barrier: values already consumed (lgkm waits inserted at uses);
// empty memory-clobber asm blocks IR motion, sched_barrier blocks MIS motion.
__device__ __forceinline__ void lds_consumer_barrier() {
    asm volatile("" ::: "memory");
    __builtin_amdgcn_s_barrier();
    __builtin_amdgcn_sched_barrier(0);
}

// ---------------------------------------------------------------------------
// K1: permuted transpose + zero-pad W_ih1 [200,300] -> Wt [300][256]
__global__ void wtrans_kernel(const float* __restrict__ W, float* __restrict__ Wt) {
    int e = blockIdx.x;        // 0..299
    int j = threadIdx.x;       // 0..255
    float v = 0.f;
    if (j < G4) {
        int row = (j & 3) * 50 + (j >> 2);
        v = W[row * EE + e];
    }
    Wt[e * JP + j] = v;
}

// ---------------------------------------------------------------------------
// K2: G1[bb][t][jp] = b1[row(jp)] + emb[x[b][t]] . W_ih1[row(jp)]
__device__ __forceinline__ float f4get(const float4& v, int u) {
    return u == 0 ? v.x : u == 1 ? v.y : u == 2 ? v.z : v.w;
}

__global__ __launch_bounds__(256) void proj_kernel(
    const int* __restrict__ x, const int* __restrict__ lengths,
    const float* __restrict__ emb, const float* __restrict__ b1,
    const float* __restrict__ Wt, float* __restrict__ G1, int b0)
{
    const int b  = b0 + blockIdx.y;
    const int t0 = blockIdx.x * 64;
    const int len = lengths[b];
    if (t0 >= len) return;                       // uniform: whole tile padding

    const int tid = threadIdx.x;
    const int rg  = tid >> 5;                    // 0..7 : rows rg*8 .. rg*8+7
    const int jg  = tid & 31;                    // col groups; valid if jg<25
    const bool active = (jg < 25);

    __shared__ float4 Ws4[BKP * 50];             // 48 KB: [k][c4]

    const float* er[8];
    #pragma unroll
    for (int q = 0; q < 8; ++q)
        er[q] = emb + (size_t)x[b * TT + t0 + rg * 8 + q] * EE;

    float acc[8][8];
    {
        float bv[8];
        #pragma unroll
        for (int k = 0; k < 8; ++k) {
            int c = (k < 4) ? (4 * jg + k) : (96 + 4 * jg + k);
            bv[k] = active ? b1[(c & 3) * 50 + (c >> 2)] : 0.f;
        }
        #pragma unroll
        for (int q = 0; q < 8; ++q)
            #pragma unroll
            for (int k = 0; k < 8; ++k) acc[q][k] = bv[k];
    }

    const float4* Wt4 = (const float4*)Wt;       // [300][64] float4s

    // 2-deep A prefetch: avn = slice e, avn2 = slice e+4
    float4 avn[8], avn2[8];
    #pragma unroll
    for (int q = 0; q < 8; ++q) avn[q]  = *(const float4*)(er[q]);
    #pragma unroll
    for (int q = 0; q < 8; ++q) avn2[q] = *(const float4*)(er[q] + 4);

    for (int s = 0; s < 5; ++s) {
        const int e0 = s * BKP;
        // ---- stage Wt[e0..e0+59][0..199] into LDS (coalesced)
        for (int i = tid; i < BKP * 50; i += 256) {
            int r = i / 50;
            int c = i - r * 50;
            Ws4[i] = Wt4[(size_t)(e0 + r) * (JP / 4) + c];
        }
        lds_producer_barrier();                   // A prefetch stays in flight

        for (int kk = 0; kk < BKP / 4; ++kk) {
            float4 av[8];
            #pragma unroll
            for (int q = 0; q < 8; ++q) { av[q] = avn[q]; avn[q] = avn2[q]; }
            int en2 = e0 + kk * 4 + 8;            // prefetch 2 slices ahead
            if (en2 > EE - 4) en2 = EE - 4;       // clamp (reload last slice)
            #pragma unroll
            for (int q = 0; q < 8; ++q)
                avn2[q] = *(const float4*)(er[q] + en2);
            if (active) {
                #pragma unroll
                for (int u = 0; u < 4; ++u) {
                    float4 w0 = Ws4[(kk * 4 + u) * 50 + jg];
                    float4 w1 = Ws4[(kk * 4 + u) * 50 + 25 + jg];
                    #pragma unroll
                    for (int q = 0; q < 8; ++q) {
                        float a = f4get(av[q], u);
                        acc[q][0] = fmaf(a, w0.x, acc[q][0]);
                        acc[q][1] = fmaf(a, w0.y, acc[q][1]);
                        acc[q][2] = fmaf(a, w0.z, acc[q][2]);
                        acc[q][3] = fmaf(a, w0.w, acc[q][3]);
                        acc[q][4] = fmaf(a, w1.x, acc[q][4]);
                        acc[q][5] = fmaf(a, w1.y, acc[q][5]);
                        acc[q][6] = fmaf(a, w1.z, acc[q][6]);
                        acc[q][7] = fmaf(a, w1.w, acc[q][7]);
                    }
                }
            }
        }
        lds_consumer_barrier();                   // Ws4 reads consumed
    }

    if (active) {
        float* gbase = G1 + ((size_t)blockIdx.y * TT + t0) * G4;
        #pragma unroll
        for (int q = 0; q < 8; ++q) {
            float* gp = gbase + (size_t)(rg * 8 + q) * G4;
            *(float4*)(gp + 4 * jg)       = make_float4(acc[q][0], acc[q][1], acc[q][2], acc[q][3]);
            *(float4*)(gp + 100 + 4 * jg) = make_float4(acc[q][4], acc[q][5], acc[q][6], acc[q][7]);
        }
    }
}

// ---------------------------------------------------------------------------
// K3: recurrence. One block (256 thr = 4 waves) per batch element.
// UNIFIED body, zero divergence:
//   tid 0..199  : LSTM1 permuted row jp=tid -> W row (jp&3)*50+(jp>>2); base=G1
//   tid 200..239: LSTM2 permuted row q=tid-200 -> row (q&3)*10+(q>>2);  base=b2
//                 (lags one step: at iter i computes h2(i-1))
//   tid 240..255: inert (zero weights)
// h state in one LDS buffer hs[2][64]: [0..49]=h1, [52..61]=h2, rest 0.
__global__ __launch_bounds__(256, 1) void lstm_kernel(
    const int* __restrict__ lengths,
    const float* __restrict__ W_hh1, const float* __restrict__ W_ih2,
    const float* __restrict__ W_hh2, const float* __restrict__ b2,
    const float* __restrict__ fc1w, const float* __restrict__ fc1b,
    const float* __restrict__ fc2w, const float* __restrict__ fc2b,
    const float* __restrict__ G1, float* __restrict__ out, int b0)
{
    const int bb  = blockIdx.x;
    const int b   = b0 + bb;
    const int tid = threadIdx.x;
    const int len = lengths[b];

    __shared__ __align__(16) float hs[2][64];
    __shared__ __align__(16) float hfin[12];
    __shared__ float zbuf[10];

    if (tid < 64) { hs[0][tid] = 0.f; hs[1][tid] = 0.f; }

    const bool isL1 = (tid < 200);
    const bool isL2 = (tid >= 200 && tid < 240);

    float wreg[52];                 // L1: W_hh1 row | L2: W_ih2 row (50 + 2 pad)
    float wregb[12];                // L2: W_hh2 row (10 + 2 pad)
    #pragma unroll
    for (int k = 0; k < 52; ++k) wreg[k] = 0.f;
    #pragma unroll
    for (int k = 0; k < 12; ++k) wregb[k] = 0.f;
    float base2 = 0.f;

    if (isL1) {
        int u = tid >> 2, g = tid & 3;
        const float* wp = W_hh1 + (g * 50 + u) * 50;
        #pragma unroll
        for (int k = 0; k < 50; ++k) wreg[k] = wp[k];
    } else if (isL2) {
        int q = tid - 200, u = q >> 2, g = q & 3;
        int row = g * 10 + u;
        const float* wp = W_ih2 + row * 50;
        #pragma unroll
        for (int k = 0; k < 50; ++k) wreg[k] = wp[k];
        const float* wp2 = W_hh2 + row * 10;
        #pragma unroll
        for (int k = 0; k < 10; ++k) wregb[k] = wp2[k];
        base2 = b2[row];
    }

    const bool wr   = ((tid & 3) == 0) && (tid < 240);
    const int  slot = isL1 ? (tid >> 2) : (52 + ((tid - 200) >> 2));

    float h1v[52], h2v[12];
    #pragma unroll
    for (int k = 0; k < 52; ++k) h1v[k] = 0.f;
    #pragma unroll
    for (int k = 0; k < 12; ++k) h2v[k] = 0.f;

    float c = 0.f;
    const float* g1p = G1 + (size_t)bb * TT * G4;
    const int gcol = isL1 ? tid : 199;           // inert/L2: harmless clamped load
    float g0, g1r, g2r;                          // 3-deep prefetch rotation
    {
        int t1 = (1 < len) ? 1 : len - 1;
        int t2 = (2 < len) ? 2 : len - 1;
        g0  = g1p[gcol];
        g1r = g1p[(size_t)t1 * G4 + gcol];
        g2r = g1p[(size_t)t2 * G4 + gcol];
    }

    __syncthreads();                              // LDS zero-init visible

    for (int i = 0; i < len; ++i) {
        float base = isL1 ? g0 : base2;
        g0 = g1r; g1r = g2r;
        int tn = (i + 3 < len) ? i + 3 : len - 1;
        g2r = g1p[(size_t)tn * G4 + gcol];        // prefetch 3 ahead (never drained)

        float s0 = 0.f, s1 = 0.f, s2 = 0.f, s3 = 0.f;
        #pragma unroll
        for (int m = 0; m < 13; ++m) {
            s0 = fmaf(wreg[4*m+0], h1v[4*m+0], s0);
            s1 = fmaf(wreg[4*m+1], h1v[4*m+1], s1);
            s2 = fmaf(wreg[4*m+2], h1v[4*m+2], s2);
            s3 = fmaf(wreg[4*m+3], h1v[4*m+3], s3);
        }
        #pragma unroll
        for (int m = 0; m < 3; ++m) {
            s0 = fmaf(wregb[4*m+0], h2v[4*m+0], s0);
            s1 = fmaf(wregb[4*m+1], h2v[4*m+1], s1);
            s2 = fmaf(wregb[4*m+2], h2v[4*m+2], s2);
            s3 = fmaf(wregb[4*m+3], h2v[4*m+3], s3);
        }
        float gv = base + (s0 + s1) + (s2 + s3);

        float gi = qb<0x00>(gv);
        float gf = qb<0x55>(gv);
        float gg = qb<0xAA>(gv);
        float go = qb<0xFF>(gv);
        float cn = sigm(gf) * c + sigm(gi) * tanh_(gg);
        float hn = sigm(go) * tanh_(cn);
        if (isL2 && i == 0) { cn = 0.f; hn = 0.f; }   // L2 lag: h2(-1)=0, c2 frozen
        c = cn;
        if (wr) hs[i & 1][slot] = hn;

        asm volatile("s_waitcnt lgkmcnt(0)" ::: "memory");
        __builtin_amdgcn_s_barrier();
        __builtin_amdgcn_sched_barrier(0);

        // broadcast-read h(i) [and h2(i-1)] into regs for next iteration
        const float* hb = hs[i & 1];
        #pragma unroll
        for (int m = 0; m < 13; ++m) {
            float4 v = *(const float4*)(hb + 4 * m);
            h1v[4*m+0] = v.x; h1v[4*m+1] = v.y;
            h1v[4*m+2] = v.z; h1v[4*m+3] = v.w;
        }
        #pragma unroll
        for (int m = 0; m < 3; ++m) {
            float4 v = *(const float4*)(hb + 52 + 4 * m);
            h2v[4*m+0] = v.x; h2v[4*m+1] = v.y;
            h2v[4*m+2] = v.z; h2v[4*m+3] = v.w;
        }
    }

    // ---- tail: L2 computes h2(len-1) from h1(len-1), h2(len-2)
    if (isL2) {
        float s0 = 0.f, s1 = 0.f, s2 = 0.f, s3 = 0.f;
        #pragma unroll
        for (int m = 0; m < 13; ++m) {
            s0 = fmaf(wreg[4*m+0], h1v[4*m+0], s0);
            s1 = fmaf(wreg[4*m+1], h1v[4*m+1], s1);
            s2 = fmaf(wreg[4*m+2], h1v[4*m+2], s2);
            s3 = fmaf(wreg[4*m+3], h1v[4*m+3], s3);
        }
        #pragma unroll
        for (int m = 0; m < 3; ++m) {
            s0 = fmaf(wregb[4*m+0], h2v[4*m+0], s0);
            s1 = fmaf(wregb[4*m+1], h2v[4*m+1], s1);
            s2 = fmaf(wregb[4*m+2], h2v[4*m+2], s2);
            s3 = fmaf(wregb[4*m+3], h2v[4*m+3], s3);
        }
        float gv = base2 + (s0 + s1) + (s2 + s3);
        float gi = qb<0x00>(gv);
        float gf = qb<0x55>(gv);
        float gg = qb<0xAA>(gv);
        float go = qb<0xFF>(gv);
        float cn = sigm(gf) * c + sigm(gi) * tanh_(gg);
        float hn = sigm(go) * tanh_(cn);
        if ((tid & 3) == 0) hfin[(tid - 200) >> 2] = hn;
    }
    __syncthreads();

    // ---- MLP head
    if (tid < 10) {
        float s = fc1b[tid];
        #pragma unroll
        for (int e = 0; e < 10; ++e) s = fmaf(fc1w[tid * 10 + e], hfin[e], s);
        zbuf[tid] = s > 0.f ? s : 0.f;
    }
    __syncthreads();
    if (tid == 0) {
        float s = fc2b[0];
        #pragma unroll
        for (int e = 0; e < 10; ++e) s = fmaf(fc2w[e], zbuf[e], s);
        out[b] = s;
    }
}

// ---------------------------------------------------------------------------
extern "C" void kernel_launch(void* const* d_in, const int* in_sizes, int n_in,
                              void* d_out, int out_size, void* d_ws, size_t ws_size,
                              hipStream_t stream)
{
    const int*   x     = (const int*)  d_in[0];
    const int*   len   = (const int*)  d_in[1];
    const float* emb   = (const float*)d_in[2];
    const float* W_ih1 = (const float*)d_in[3];
    const float* W_hh1 = (const float*)d_in[4];
    const float* b1    = (const float*)d_in[5];
    const float* W_ih2 = (const float*)d_in[6];
    const float* W_hh2 = (const float*)d_in[7];
    const float* b2    = (const float*)d_in[8];
    const float* fc1w  = (const float*)d_in[9];
    const float* fc1b  = (const float*)d_in[10];
    const float* fc2w  = (const float*)d_in[11];
    const float* fc2b  = (const float*)d_in[12];
    float* out = (float*)d_out;

    const size_t wt_bytes = (size_t)EE * JP * sizeof(float);     // 307200
    const size_t per_b    = (size_t)TT * G4 * sizeof(float);     // 409600
    float* Wt = (float*)d_ws;
    float* G1 = (float*)((char*)d_ws + wt_bytes);

    size_t avail = ws_size > wt_bytes ? ws_size - wt_bytes : 0;
    int chunk = (int)(avail / per_b);
    if (chunk < 1) chunk = 1;
    if (chunk > BB) chunk = BB;

    wtrans_kernel<<<dim3(EE), dim3(256), 0, stream>>>(W_ih1, Wt);

    for (int b0 = 0; b0 < BB; b0 += chunk) {
        int nb = (BB - b0) < chunk ? (BB - b0) : chunk;
        proj_kernel<<<dim3(TT / 64, nb), dim3(256), 0, stream>>>(
            x, len, emb, b1, Wt, G1, b0);
        lstm_kernel<<<dim3(nb), dim3(256), 0, stream>>>(
            len, W_hh1, W_ih2, W_hh2, b2, fc1w, fc1b, fc2w, fc2b, G1, out, b0);
    }
}